// Round 2
// baseline (220.732 us; speedup 1.0000x reference)
//
#include <hip/hip_runtime.h>
#include <math.h>

// WayfinderAttention: B=1, H=16, T=2048, DH=64, D=64 neighbors. f32 in/out.
// One wave per query. R2: cooperative (coalesced) staging of the 64 gathered
// K rows into LDS as bf16 with XOR-swizzled 16B chunks (bank-uniform reads
// and writes, row stride exactly 128B). Invalid rows are exec-mask-skipped.
// This cuts vector-memory cache-line requests ~3.5x vs per-lane row gathers.

#define T_DIM 2048
#define DH    64
#define NB    64
#define WPB   4   // waves per block

__global__ __launch_bounds__(WPB * 64)
void wayfinder_attn_kernel(const float* __restrict__ q,
                           const float* __restrict__ k,
                           const float* __restrict__ v,
                           const float* __restrict__ etb,   // 4 floats
                           const int*   __restrict__ neigh_idx,
                           const int*   __restrict__ edge_type,
                           float*       __restrict__ out)
{
    // K rows as bf16: 64 rows x 128B (32 uints), XOR-swizzled 16B chunks.
    __shared__ unsigned int k_s[WPB][NB * 32];
    __shared__ float        q_s[WPB][DH];

    const int lane = threadIdx.x & 63;
    const int wave = threadIdx.x >> 6;
    const int wq   = blockIdx.x * WPB + wave;        // flat h*T + t (B=1)
    const int t    = wq & (T_DIM - 1);
    const long long qbase    = (long long)wq * DH;
    const long long headbase = (long long)(wq - t) * DH;  // this head's K/V base

    // stage q (coalesced 256B)
    q_s[wave][lane] = q[qbase + lane];

    // per-lane neighbor metadata (lane d owns neighbor d)
    const long long nbase = (long long)wq * NB;
    const int raw = neigh_idx[nbase + lane];
    const int et  = edge_type[nbase + lane];
    const bool valid = (raw >= 0) && (raw <= t);
    const int  sj   = min(max(raw, 0), T_DIM - 1);
    const int  okj  = valid ? sj : -1;

    // ---- cooperative K staging: 16 lanes per row, 4 rows per iteration ----
    // lane -> (row-sublane rsub = lane>>4, float4-chunk c = lane&15)
    {
        const int c    = lane & 15;
        const int rsub = lane >> 4;
        const float* __restrict__ khead = k + headbase;
        #pragma unroll 4
        for (int i = 0; i < 16; ++i) {
            const int r   = i * 4 + rsub;
            const int sjr = __shfl(okj, r, 64);
            if (sjr >= 0) {
                const float4 kv = *(const float4*)(khead + (long long)sjr * DH + c * 4);
                // pack 4 f32 -> 4 bf16 (truncate)
                const unsigned int ax = __float_as_uint(kv.x);
                const unsigned int ay = __float_as_uint(kv.y);
                const unsigned int az = __float_as_uint(kv.z);
                const unsigned int aw = __float_as_uint(kv.w);
                uint2 p;
                p.x = (ax >> 16) | (ay & 0xffff0000u);   // elems 4c, 4c+1
                p.y = (az >> 16) | (aw & 0xffff0000u);   // elems 4c+2, 4c+3
                // swizzled 16B-chunk position within the row
                const int chunk = (c >> 1) ^ (r & 7);
                const int half  = c & 1;
                *(uint2*)&k_s[wave][r * 32 + chunk * 4 + half * 2] = p;
            }
        }
    }
    __syncthreads();

    // ---- score: lane d dots q (f32, LDS broadcast) with its bf16 K row ----
    float dot = 0.f;
    if (valid) {
        const unsigned int* __restrict__ krow = &k_s[wave][lane * 32];
        const float4* __restrict__ qs4 = (const float4*)q_s[wave];
        const int sw = lane & 7;
        #pragma unroll
        for (int j = 0; j < 8; ++j) {
            const int cj = j ^ sw;
            const uint4 u = *(const uint4*)(krow + cj * 4);   // dims 8j..8j+7
            const float4 q0 = qs4[2 * j];
            const float4 q1 = qs4[2 * j + 1];
            dot += __uint_as_float(u.x << 16)         * q0.x;
            dot += __uint_as_float(u.x & 0xffff0000u) * q0.y;
            dot += __uint_as_float(u.y << 16)         * q0.z;
            dot += __uint_as_float(u.y & 0xffff0000u) * q0.w;
            dot += __uint_as_float(u.z << 16)         * q1.x;
            dot += __uint_as_float(u.z & 0xffff0000u) * q1.y;
            dot += __uint_as_float(u.w << 16)         * q1.z;
            dot += __uint_as_float(u.w & 0xffff0000u) * q1.w;
        }
    }
    const float bias  = (et != 0) ? etb[et - 1] : 0.f;
    const float score = valid ? (dot * 0.125f + bias) : -INFINITY;

    // ---- wave-wide masked softmax ----
    float m = score;
    #pragma unroll
    for (int o = 32; o > 0; o >>= 1) m = fmaxf(m, __shfl_xor(m, o, 64));
    const float e = valid ? __expf(score - m) : 0.f;
    float s = e;
    #pragma unroll
    for (int o = 32; o > 0; o >>= 1) s += __shfl_xor(s, o, 64);
    const float w = e / fmaxf(s, 1e-20f);

    // ---- PV: iterate valid neighbors; coalesced 256B V-row loads ----
    float acc = 0.f;
    unsigned long long vb = __ballot(valid);
    const float* __restrict__ vhead = v + headbase;
    while (vb) {
        const int d = __builtin_ctzll(vb);
        vb &= vb - 1;
        const float wd = __shfl(w, d, 64);
        const int   jd = __shfl(sj, d, 64);
        acc += wd * vhead[jd * DH + lane];
    }
    out[qbase + lane] = acc;
}

extern "C" void kernel_launch(void* const* d_in, const int* in_sizes, int n_in,
                              void* d_out, int out_size, void* d_ws, size_t ws_size,
                              hipStream_t stream)
{
    const float* q   = (const float*)d_in[0];
    const float* k   = (const float*)d_in[1];
    const float* v   = (const float*)d_in[2];
    const float* etb = (const float*)d_in[3];
    const int* neigh_idx = (const int*)d_in[4];
    const int* edge_type = (const int*)d_in[5];
    float* out = (float*)d_out;

    const int total_queries = 16 * T_DIM;     // B*H*T = 32768
    const int blocks = total_queries / WPB;   // 8192
    hipLaunchKernelGGL(wayfinder_attn_kernel, dim3(blocks), dim3(WPB * 64),
                       0, stream, q, k, v, etb, neigh_idx, edge_type, out);
}

// Round 3
// 136.886 us; speedup vs baseline: 1.6125x; 1.6125x over previous
//
#include <hip/hip_runtime.h>
#include <math.h>

// WayfinderAttention: B=1, H=16, T=2048, DH=64, D=64 neighbors. f32 in/out.
// One wave per query. R3: branch-free cooperative gather with max MLP.
//  - Score: group g (16 lanes) handles row g*16+i at unrolled iter i; per-lane
//    16B chunk load (clamped idx, unconditional), partial dot vs q-chunk,
//    DPP shfl_xor reduction over the group; owner lane (c==i) keeps the dot.
//  - PV: fixed 64-trip unrolled loop, weights/indices broadcast from LDS,
//    invalid neighbors zeroed by weight. Coalesced 256B V-row loads.
// LDS = 2KB/block, no __syncthreads, f32 end-to-end.

#define T_DIM 2048
#define DH    64
#define NB    64
#define WPB   4   // waves per block

__global__ __launch_bounds__(WPB * 64)
void wayfinder_attn_kernel(const float* __restrict__ q,
                           const float* __restrict__ k,
                           const float* __restrict__ v,
                           const float* __restrict__ etb,   // 4 floats
                           const int*   __restrict__ neigh_idx,
                           const int*   __restrict__ edge_type,
                           float*       __restrict__ out)
{
    __shared__ int   j_s[WPB][NB];
    __shared__ float w_s[WPB][NB];

    const int lane = threadIdx.x & 63;
    const int wave = threadIdx.x >> 6;
    const int wq   = blockIdx.x * WPB + wave;        // flat h*T + t (B=1)
    const int t    = wq & (T_DIM - 1);
    const long long qbase    = (long long)wq * DH;
    const long long headbase = (long long)(wq - t) * DH;  // this head's K/V base

    // per-lane neighbor metadata (lane d owns neighbor d)
    const long long nbase = (long long)wq * NB;
    const int raw = neigh_idx[nbase + lane];
    const int et  = edge_type[nbase + lane];
    const bool valid = (raw >= 0) && (raw <= t);
    const int  sj   = min(max(raw, 0), T_DIM - 1);   // clamped: always loadable
    j_s[wave][lane] = sj;

    // my q chunk: group position c covers q dims 4c..4c+3 (broadcast x4 groups)
    const int c = lane & 15;
    const int g = lane >> 4;
    const float4 qv = *(const float4*)(q + qbase + c * 4);

    // pre-read my group's 16 row indices (4x ds_read_b128 -> registers)
    int jarr[16];
    {
        const int4* jg = (const int4*)&j_s[wave][g * 16];
        *(int4*)&jarr[0]  = jg[0];
        *(int4*)&jarr[4]  = jg[1];
        *(int4*)&jarr[8]  = jg[2];
        *(int4*)&jarr[12] = jg[3];
    }

    // ---- score phase: 16 independent, branch-free iterations ----
    const float* __restrict__ khead = k + headbase;
    float mydot = 0.f;
    #pragma unroll
    for (int i = 0; i < 16; ++i) {
        const float4 kv = *(const float4*)(khead + (long long)jarr[i] * DH + c * 4);
        float p = kv.x * qv.x + kv.y * qv.y + kv.z * qv.z + kv.w * qv.w;
        p += __shfl_xor(p, 1, 64);   // DPP, stays within 16-lane group
        p += __shfl_xor(p, 2, 64);
        p += __shfl_xor(p, 4, 64);
        p += __shfl_xor(p, 8, 64);
        if (c == i) mydot = p;       // lane g*16+i owns neighbor g*16+i
    }

    const float bias  = (et != 0) ? etb[et - 1] : 0.f;
    const float score = valid ? (mydot * 0.125f + bias) : -INFINITY;

    // ---- wave-wide masked softmax ----
    float m = score;
    #pragma unroll
    for (int o = 32; o > 0; o >>= 1) m = fmaxf(m, __shfl_xor(m, o, 64));
    const float e = valid ? __expf(score - m) : 0.f;
    float s = e;
    #pragma unroll
    for (int o = 32; o > 0; o >>= 1) s += __shfl_xor(s, o, 64);
    const float w = e / fmaxf(s, 1e-20f);
    w_s[wave][lane] = w;

    // ---- PV: fixed 64-trip unrolled loop, broadcast (w,j), coalesced loads ----
    const float* __restrict__ vhead = v + headbase;
    float acc = 0.f;
    #pragma unroll
    for (int d4 = 0; d4 < 16; ++d4) {
        const float4 wd = *(const float4*)&w_s[wave][d4 * 4];   // broadcast
        const int4   jd = *(const int4*)&j_s[wave][d4 * 4];     // broadcast
        acc += wd.x * vhead[(long long)jd.x * DH + lane];
        acc += wd.y * vhead[(long long)jd.y * DH + lane];
        acc += wd.z * vhead[(long long)jd.z * DH + lane];
        acc += wd.w * vhead[(long long)jd.w * DH + lane];
    }
    out[qbase + lane] = acc;
}

extern "C" void kernel_launch(void* const* d_in, const int* in_sizes, int n_in,
                              void* d_out, int out_size, void* d_ws, size_t ws_size,
                              hipStream_t stream)
{
    const float* q   = (const float*)d_in[0];
    const float* k   = (const float*)d_in[1];
    const float* v   = (const float*)d_in[2];
    const float* etb = (const float*)d_in[3];
    const int* neigh_idx = (const int*)d_in[4];
    const int* edge_type = (const int*)d_in[5];
    float* out = (float*)d_out;

    const int total_queries = 16 * T_DIM;     // B*H*T = 32768
    const int blocks = total_queries / WPB;   // 8192
    hipLaunchKernelGGL(wayfinder_attn_kernel, dim3(blocks), dim3(WPB * 64),
                       0, stream, q, k, v, etb, neigh_idx, edge_type, out);
}

// Round 4
// 123.662 us; speedup vs baseline: 1.7850x; 1.1069x over previous
//
#include <hip/hip_runtime.h>
#include <math.h>

// WayfinderAttention: B=1, H=16, T=2048, DH=64, D=64 neighbors. f32 in/out.
// R4: (1) prepass converts K,V to bf16 (truncate) in d_ws -> halves gather
//     bytes/requests; (2) valid-neighbor compaction via ballot+prefix ->
//     score loop does only nv rows, PV trip count is wave-uniform ceil(nv/16);
//     (3) wider chunks: score 8 lanes/row x 16B, PV 16 lanes/row x 8B.
// Softmax over the compacted (all-valid) set == reference masked softmax.
// Fallback to the R3 f32 kernel if ws_size < 8 MB.

#define T_DIM 2048
#define DH    64
#define NB    64
#define WPB   4
#define KV_ELEMS (16 * T_DIM * DH)   // 2,097,152 per tensor

// ---------------- prepass: pack f32 -> bf16 pairs ----------------
__global__ __launch_bounds__(256)
void convert_kv_kernel(const float* __restrict__ k, const float* __restrict__ v,
                       unsigned int* __restrict__ ws)
{
    const int tid = blockIdx.x * 256 + threadIdx.x;     // [0, KV_ELEMS/4)
    unsigned int* kh = ws;
    unsigned int* vh = ws + (KV_ELEMS / 2);
    const float4 kv = *(const float4*)(k + (long long)tid * 4);
    const float4 vv = *(const float4*)(v + (long long)tid * 4);
    uint2 pk, pv;
    pk.x = (__float_as_uint(kv.x) >> 16) | (__float_as_uint(kv.y) & 0xffff0000u);
    pk.y = (__float_as_uint(kv.z) >> 16) | (__float_as_uint(kv.w) & 0xffff0000u);
    pv.x = (__float_as_uint(vv.x) >> 16) | (__float_as_uint(vv.y) & 0xffff0000u);
    pv.y = (__float_as_uint(vv.z) >> 16) | (__float_as_uint(vv.w) & 0xffff0000u);
    *(uint2*)(kh + tid * 2) = pk;
    *(uint2*)(vh + tid * 2) = pv;
}

__device__ __forceinline__ float bflo(unsigned int u) { return __uint_as_float(u << 16); }
__device__ __forceinline__ float bfhi(unsigned int u) { return __uint_as_float(u & 0xffff0000u); }

// ---------------- main kernel (bf16 gathers, compacted) ----------------
__global__ __launch_bounds__(WPB * 64)
void wayfinder_attn_bf16(const float* __restrict__ q,
                         const unsigned int* __restrict__ kvws,
                         const float* __restrict__ etb,
                         const int*   __restrict__ neigh_idx,
                         const int*   __restrict__ edge_type,
                         float*       __restrict__ out)
{
    __shared__ int   j_s[WPB][NB];
    __shared__ float b_s[WPB][NB];
    __shared__ float w_s[WPB][NB];

    const int lane = threadIdx.x & 63;
    const int wave = threadIdx.x >> 6;
    const int wq   = blockIdx.x * WPB + wave;       // flat h*T + t (B=1)
    const int t    = wq & (T_DIM - 1);
    const int qbase    = wq * DH;
    const int headbase = (wq - t) * DH;             // floats
    const unsigned int* __restrict__ kh = kvws + (headbase >> 1);
    const unsigned int* __restrict__ vh = kvws + (KV_ELEMS / 2) + (headbase >> 1);

    // init padding (entries >= nv read as row 0 / bias 0)
    j_s[wave][lane] = 0;
    b_s[wave][lane] = 0.f;

    // per-lane neighbor metadata (lane d owns raw neighbor slot d)
    const int raw = neigh_idx[wq * NB + lane];
    const int et  = edge_type[wq * NB + lane];
    const bool valid = (raw >= 0) && (raw <= t);
    const int  sj    = min(max(raw, 0), T_DIM - 1);
    const float bias = (et != 0) ? etb[et - 1] : 0.f;

    // compaction: valid entries -> positions [0, nv)
    const unsigned long long vb = __ballot(valid);
    const int nv  = __popcll(vb);
    const int pos = __popcll(vb & ((1ull << lane) - 1ull));
    if (valid) { j_s[wave][pos] = sj; b_s[wave][pos] = bias; }

    // ---- score phase: 8-lane groups, group g8 handles entries g8*8+i ----
    const int c8 = lane & 7;
    const int g8 = lane >> 3;
    const float4 qv0 = *(const float4*)(q + qbase + c8 * 8);
    const float4 qv1 = *(const float4*)(q + qbase + c8 * 8 + 4);

    int jarr[8];
    {
        const int4* jg = (const int4*)&j_s[wave][g8 * 8];
        *(int4*)&jarr[0] = jg[0];
        *(int4*)&jarr[4] = jg[1];
    }
    const int mycnt = nv - g8 * 8;   // group-uniform; may be <=0
    float mydot = 0.f;
    #pragma unroll
    for (int i = 0; i < 8; ++i) {
        if (i < mycnt) {
            const uint4 u = *(const uint4*)(kh + jarr[i] * 32 + c8 * 4);  // dims 8c8..8c8+7
            float p = bflo(u.x) * qv0.x + bfhi(u.x) * qv0.y
                    + bflo(u.y) * qv0.z + bfhi(u.y) * qv0.w
                    + bflo(u.z) * qv1.x + bfhi(u.z) * qv1.y
                    + bflo(u.w) * qv1.z + bfhi(u.w) * qv1.w;
            p += __shfl_xor(p, 1, 64);
            p += __shfl_xor(p, 2, 64);
            p += __shfl_xor(p, 4, 64);
            if (c8 == i) mydot = p;   // lane g8*8+i == entry index e
        }
    }

    // ---- softmax over compacted entries (lane d = entry d) ----
    const bool dval = lane < nv;
    const float score = dval ? (mydot * 0.125f + b_s[wave][lane]) : -INFINITY;
    float m = score;
    #pragma unroll
    for (int o = 32; o > 0; o >>= 1) m = fmaxf(m, __shfl_xor(m, o, 64));
    const float e = dval ? __expf(score - m) : 0.f;
    float s = e;
    #pragma unroll
    for (int o = 32; o > 0; o >>= 1) s += __shfl_xor(s, o, 64);
    const float w = e / fmaxf(s, 1e-20f);
    w_s[wave][lane] = w;   // entries >= nv get w=0 (padding-safe)

    // ---- PV: quarter-wave per row (16 lanes x 8B), 16 entries per chunk ----
    const int qw   = lane >> 4;      // quarter 0..3
    const int lp16 = lane & 15;      // position in quarter: dims 4*lp16..+3
    float a0 = 0.f, a1 = 0.f, a2 = 0.f, a3 = 0.f;
    for (int base = 0; base < nv; base += 16) {
        #pragma unroll
        for (int ii = 0; ii < 4; ++ii) {
            const int e2 = base + ii * 4 + qw;          // <= 63
            const float we = w_s[wave][e2];
            const int   je = j_s[wave][e2];
            const uint2 uv = *(const uint2*)(vh + je * 32 + lp16 * 2);
            a0 += we * bflo(uv.x);
            a1 += we * bfhi(uv.x);
            a2 += we * bflo(uv.y);
            a3 += we * bfhi(uv.y);
        }
    }
    // reduce across quarters (butterfly), then lanes 0..15 store float4
    a0 += __shfl_xor(a0, 16, 64);  a1 += __shfl_xor(a1, 16, 64);
    a2 += __shfl_xor(a2, 16, 64);  a3 += __shfl_xor(a3, 16, 64);
    a0 += __shfl_xor(a0, 32, 64);  a1 += __shfl_xor(a1, 32, 64);
    a2 += __shfl_xor(a2, 32, 64);  a3 += __shfl_xor(a3, 32, 64);
    if (lane < 16) {
        float4 o; o.x = a0; o.y = a1; o.z = a2; o.w = a3;
        *(float4*)(out + qbase + lane * 4) = o;
    }
}

// ---------------- fallback (R3, f32, no workspace) ----------------
__global__ __launch_bounds__(WPB * 64)
void wayfinder_attn_f32(const float* __restrict__ q,
                        const float* __restrict__ k,
                        const float* __restrict__ v,
                        const float* __restrict__ etb,
                        const int*   __restrict__ neigh_idx,
                        const int*   __restrict__ edge_type,
                        float*       __restrict__ out)
{
    __shared__ int   j_s[WPB][NB];
    __shared__ float w_s[WPB][NB];

    const int lane = threadIdx.x & 63;
    const int wave = threadIdx.x >> 6;
    const int wq   = blockIdx.x * WPB + wave;
    const int t    = wq & (T_DIM - 1);
    const long long qbase    = (long long)wq * DH;
    const long long headbase = (long long)(wq - t) * DH;

    const long long nbase = (long long)wq * NB;
    const int raw = neigh_idx[nbase + lane];
    const int et  = edge_type[nbase + lane];
    const bool valid = (raw >= 0) && (raw <= t);
    const int  sj   = min(max(raw, 0), T_DIM - 1);
    j_s[wave][lane] = sj;

    const int c = lane & 15;
    const int g = lane >> 4;
    const float4 qv = *(const float4*)(q + qbase + c * 4);

    int jarr[16];
    {
        const int4* jg = (const int4*)&j_s[wave][g * 16];
        *(int4*)&jarr[0]  = jg[0];
        *(int4*)&jarr[4]  = jg[1];
        *(int4*)&jarr[8]  = jg[2];
        *(int4*)&jarr[12] = jg[3];
    }

    const float* __restrict__ khead = k + headbase;
    float mydot = 0.f;
    #pragma unroll
    for (int i = 0; i < 16; ++i) {
        const float4 kv = *(const float4*)(khead + (long long)jarr[i] * DH + c * 4);
        float p = kv.x * qv.x + kv.y * qv.y + kv.z * qv.z + kv.w * qv.w;
        p += __shfl_xor(p, 1, 64);
        p += __shfl_xor(p, 2, 64);
        p += __shfl_xor(p, 4, 64);
        p += __shfl_xor(p, 8, 64);
        if (c == i) mydot = p;
    }

    const float bias  = (et != 0) ? etb[et - 1] : 0.f;
    const float score = valid ? (mydot * 0.125f + bias) : -INFINITY;

    float m = score;
    #pragma unroll
    for (int o = 32; o > 0; o >>= 1) m = fmaxf(m, __shfl_xor(m, o, 64));
    const float e = valid ? __expf(score - m) : 0.f;
    float s = e;
    #pragma unroll
    for (int o = 32; o > 0; o >>= 1) s += __shfl_xor(s, o, 64);
    const float w = e / fmaxf(s, 1e-20f);
    w_s[wave][lane] = w;

    const float* __restrict__ vhead = v + headbase;
    float acc = 0.f;
    #pragma unroll
    for (int d4 = 0; d4 < 16; ++d4) {
        const float4 wd = *(const float4*)&w_s[wave][d4 * 4];
        const int4   jd = *(const int4*)&j_s[wave][d4 * 4];
        acc += wd.x * vhead[(long long)jd.x * DH + lane];
        acc += wd.y * vhead[(long long)jd.y * DH + lane];
        acc += wd.z * vhead[(long long)jd.z * DH + lane];
        acc += wd.w * vhead[(long long)jd.w * DH + lane];
    }
    out[qbase + lane] = acc;
}

extern "C" void kernel_launch(void* const* d_in, const int* in_sizes, int n_in,
                              void* d_out, int out_size, void* d_ws, size_t ws_size,
                              hipStream_t stream)
{
    const float* q   = (const float*)d_in[0];
    const float* k   = (const float*)d_in[1];
    const float* v   = (const float*)d_in[2];
    const float* etb = (const float*)d_in[3];
    const int* neigh_idx = (const int*)d_in[4];
    const int* edge_type = (const int*)d_in[5];
    float* out = (float*)d_out;

    const int total_queries = 16 * T_DIM;     // 32768
    const int blocks = total_queries / WPB;   // 8192
    const size_t need = (size_t)KV_ELEMS * 2 * sizeof(unsigned short); // 8 MB

    if (ws_size >= need) {
        unsigned int* ws = (unsigned int*)d_ws;
        hipLaunchKernelGGL(convert_kv_kernel, dim3(KV_ELEMS / 4 / 256), dim3(256),
                           0, stream, k, v, ws);
        hipLaunchKernelGGL(wayfinder_attn_bf16, dim3(blocks), dim3(WPB * 64),
                           0, stream, q, ws, etb, neigh_idx, edge_type, out);
    } else {
        hipLaunchKernelGGL(wayfinder_attn_f32, dim3(blocks), dim3(WPB * 64),
                           0, stream, q, k, v, etb, neigh_idx, edge_type, out);
    }
}

// Round 7
// 122.361 us; speedup vs baseline: 1.8039x; 1.0106x over previous
//
#include <hip/hip_runtime.h>
#include <hip/hip_fp16.h>
#include <math.h>

// WayfinderAttention: B=1, H=16, T=2048, DH=64, D=64 neighbors. f32 in/out.
// R7: ISOLATION ROUND. Exact R4 skeleton (passed, absmax 0.031): blocked
//     score order g8*8+i with `i<mycnt` guard and c8==i capture, per-lane nv,
//     f32 weights, f32 PV accumulation, runtime PV loop. Single delta vs R4:
//     K/V stored as f16 (RTN) instead of bf16 (truncate); unpack via
//     cvt_f32_f16 instead of shifts (same op count).
// Fallback to the proven R3 f32 kernel if ws_size < 8 MB.

#define T_DIM 2048
#define DH    64
#define NB    64
#define WPB   4
#define KV_ELEMS (16 * T_DIM * DH)   // 2,097,152 per tensor

typedef _Float16 h2_t __attribute__((ext_vector_type(2)));

// ---------------- prepass: f32 -> f16 (RTN), K then V ----------------
__global__ __launch_bounds__(256)
void convert_kv_kernel(const float* __restrict__ k, const float* __restrict__ v,
                       unsigned int* __restrict__ ws)
{
    const int tid = blockIdx.x * 256 + threadIdx.x;     // [0, KV_ELEMS/4)
    unsigned int* kh = ws;
    unsigned int* vh = ws + (KV_ELEMS / 2);
    const float4 kv = *(const float4*)(k + (long long)tid * 4);
    const float4 vv = *(const float4*)(v + (long long)tid * 4);
    h2_t k0 = { (_Float16)kv.x, (_Float16)kv.y };
    h2_t k1 = { (_Float16)kv.z, (_Float16)kv.w };
    h2_t v0 = { (_Float16)vv.x, (_Float16)vv.y };
    h2_t v1 = { (_Float16)vv.z, (_Float16)vv.w };
    uint2 pk, pv;
    pk.x = __builtin_bit_cast(unsigned int, k0);
    pk.y = __builtin_bit_cast(unsigned int, k1);
    pv.x = __builtin_bit_cast(unsigned int, v0);
    pv.y = __builtin_bit_cast(unsigned int, v1);
    *(uint2*)(kh + tid * 2) = pk;
    *(uint2*)(vh + tid * 2) = pv;
}

__device__ __forceinline__ float f16lo(unsigned int u) {
    return __low2float(__builtin_bit_cast(__half2, u));
}
__device__ __forceinline__ float f16hi(unsigned int u) {
    return __high2float(__builtin_bit_cast(__half2, u));
}

// ---------------- main kernel (f16 gathers, compacted; R4 structure) ----------------
__global__ __launch_bounds__(WPB * 64)
void wayfinder_attn_f16(const float* __restrict__ q,
                        const unsigned int* __restrict__ kvws,
                        const float* __restrict__ etb,
                        const int*   __restrict__ neigh_idx,
                        const int*   __restrict__ edge_type,
                        float*       __restrict__ out)
{
    __shared__ int   j_s[WPB][NB];
    __shared__ float b_s[WPB][NB];
    __shared__ float w_s[WPB][NB];

    const int lane = threadIdx.x & 63;
    const int wave = threadIdx.x >> 6;
    const int wq   = blockIdx.x * WPB + wave;       // flat h*T + t (B=1)
    const int t    = wq & (T_DIM - 1);
    const int qbase    = wq * DH;
    const int headbase = (wq - t) * DH;             // floats
    const unsigned int* __restrict__ kh = kvws + (headbase >> 1);
    const unsigned int* __restrict__ vh = kvws + (KV_ELEMS / 2) + (headbase >> 1);

    // init padding (entries >= nv read as row 0 / bias 0)
    j_s[wave][lane] = 0;
    b_s[wave][lane] = 0.f;

    // per-lane neighbor metadata (lane d owns raw neighbor slot d)
    const int raw = neigh_idx[wq * NB + lane];
    const int et  = edge_type[wq * NB + lane];
    const bool valid = (raw >= 0) && (raw <= t);
    const int  sj    = min(max(raw, 0), T_DIM - 1);
    const float bias = (et != 0) ? etb[et - 1] : 0.f;

    // compaction: valid entries -> positions [0, nv)
    const unsigned long long vb = __ballot(valid);
    const int nv  = __popcll(vb);
    const int pos = __popcll(vb & ((1ull << lane) - 1ull));
    if (valid) { j_s[wave][pos] = sj; b_s[wave][pos] = bias; }

    // ---- score phase: 8-lane groups, group g8 handles entries g8*8+i ----
    const int c8 = lane & 7;
    const int g8 = lane >> 3;
    const float4 qv0 = *(const float4*)(q + qbase + c8 * 8);
    const float4 qv1 = *(const float4*)(q + qbase + c8 * 8 + 4);

    int jarr[8];
    {
        const int4* jg = (const int4*)&j_s[wave][g8 * 8];
        *(int4*)&jarr[0] = jg[0];
        *(int4*)&jarr[4] = jg[1];
    }
    const int mycnt = nv - g8 * 8;   // group-uniform; may be <=0
    float mydot = 0.f;
    #pragma unroll
    for (int i = 0; i < 8; ++i) {
        if (i < mycnt) {
            const uint4 u = *(const uint4*)(kh + jarr[i] * 32 + c8 * 4);  // dims 8c8..8c8+7
            float p = f16lo(u.x) * qv0.x + f16hi(u.x) * qv0.y
                    + f16lo(u.y) * qv0.z + f16hi(u.y) * qv0.w
                    + f16lo(u.z) * qv1.x + f16hi(u.z) * qv1.y
                    + f16lo(u.w) * qv1.z + f16hi(u.w) * qv1.w;
            p += __shfl_xor(p, 1, 64);
            p += __shfl_xor(p, 2, 64);
            p += __shfl_xor(p, 4, 64);
            if (c8 == i) mydot = p;   // lane g8*8+i == entry index e
        }
    }

    // ---- softmax over compacted entries (lane d = entry d) ----
    const bool dval = lane < nv;
    const float score = dval ? (mydot * 0.125f + b_s[wave][lane]) : -INFINITY;
    float m = score;
    #pragma unroll
    for (int o = 32; o > 0; o >>= 1) m = fmaxf(m, __shfl_xor(m, o, 64));
    const float e = dval ? __expf(score - m) : 0.f;
    float s = e;
    #pragma unroll
    for (int o = 32; o > 0; o >>= 1) s += __shfl_xor(s, o, 64);
    const float w = e / fmaxf(s, 1e-20f);
    w_s[wave][lane] = w;   // entries >= nv get w=0 (padding-safe)

    // ---- PV: quarter-wave per row (16 lanes x 8B), 16 entries per chunk ----
    const int qw   = lane >> 4;      // quarter 0..3
    const int lp16 = lane & 15;      // position in quarter: dims 4*lp16..+3
    float a0 = 0.f, a1 = 0.f, a2 = 0.f, a3 = 0.f;
    for (int base = 0; base < nv; base += 16) {
        #pragma unroll
        for (int ii = 0; ii < 4; ++ii) {
            const int e2 = base + ii * 4 + qw;          // <= 63
            const float we = w_s[wave][e2];
            const int   je = j_s[wave][e2];
            const uint2 uv = *(const uint2*)(vh + je * 32 + lp16 * 2);
            a0 += we * f16lo(uv.x);
            a1 += we * f16hi(uv.x);
            a2 += we * f16lo(uv.y);
            a3 += we * f16hi(uv.y);
        }
    }
    // reduce across quarters (butterfly), then lanes 0..15 store float4
    a0 += __shfl_xor(a0, 16, 64);  a1 += __shfl_xor(a1, 16, 64);
    a2 += __shfl_xor(a2, 16, 64);  a3 += __shfl_xor(a3, 16, 64);
    a0 += __shfl_xor(a0, 32, 64);  a1 += __shfl_xor(a1, 32, 64);
    a2 += __shfl_xor(a2, 32, 64);  a3 += __shfl_xor(a3, 32, 64);
    if (lane < 16) {
        float4 o; o.x = a0; o.y = a1; o.z = a2; o.w = a3;
        *(float4*)(out + qbase + lane * 4) = o;
    }
}

// ---------------- fallback (R3, f32, no workspace) ----------------
__global__ __launch_bounds__(WPB * 64)
void wayfinder_attn_f32(const float* __restrict__ q,
                        const float* __restrict__ k,
                        const float* __restrict__ v,
                        const float* __restrict__ etb,
                        const int*   __restrict__ neigh_idx,
                        const int*   __restrict__ edge_type,
                        float*       __restrict__ out)
{
    __shared__ int   j_s[WPB][NB];
    __shared__ float w_s[WPB][NB];

    const int lane = threadIdx.x & 63;
    const int wave = threadIdx.x >> 6;
    const int wq   = blockIdx.x * WPB + wave;
    const int t    = wq & (T_DIM - 1);
    const long long qbase    = (long long)wq * DH;
    const long long headbase = (long long)(wq - t) * DH;

    const long long nbase = (long long)wq * NB;
    const int raw = neigh_idx[nbase + lane];
    const int et  = edge_type[nbase + lane];
    const bool valid = (raw >= 0) && (raw <= t);
    const int  sj   = min(max(raw, 0), T_DIM - 1);
    j_s[wave][lane] = sj;

    const int c = lane & 15;
    const int g = lane >> 4;
    const float4 qv = *(const float4*)(q + qbase + c * 4);

    int jarr[16];
    {
        const int4* jg = (const int4*)&j_s[wave][g * 16];
        *(int4*)&jarr[0]  = jg[0];
        *(int4*)&jarr[4]  = jg[1];
        *(int4*)&jarr[8]  = jg[2];
        *(int4*)&jarr[12] = jg[3];
    }

    const float* __restrict__ khead = k + headbase;
    float mydot = 0.f;
    #pragma unroll
    for (int i = 0; i < 16; ++i) {
        const float4 kv = *(const float4*)(khead + (long long)jarr[i] * DH + c * 4);
        float p = kv.x * qv.x + kv.y * qv.y + kv.z * qv.z + kv.w * qv.w;
        p += __shfl_xor(p, 1, 64);
        p += __shfl_xor(p, 2, 64);
        p += __shfl_xor(p, 4, 64);
        p += __shfl_xor(p, 8, 64);
        if (c == i) mydot = p;
    }

    const float bias  = (et != 0) ? etb[et - 1] : 0.f;
    const float score = valid ? (mydot * 0.125f + bias) : -INFINITY;

    float m = score;
    #pragma unroll
    for (int o = 32; o > 0; o >>= 1) m = fmaxf(m, __shfl_xor(m, o, 64));
    const float e = valid ? __expf(score - m) : 0.f;
    float s = e;
    #pragma unroll
    for (int o = 32; o > 0; o >>= 1) s += __shfl_xor(s, o, 64);
    const float w = e / fmaxf(s, 1e-20f);
    w_s[wave][lane] = w;

    const float* __restrict__ vhead = v + headbase;
    float acc = 0.f;
    #pragma unroll
    for (int d4 = 0; d4 < 16; ++d4) {
        const float4 wd = *(const float4*)&w_s[wave][d4 * 4];
        const int4   jd = *(const int4*)&j_s[wave][d4 * 4];
        acc += wd.x * vhead[(long long)jd.x * DH + lane];
        acc += wd.y * vhead[(long long)jd.y * DH + lane];
        acc += wd.z * vhead[(long long)jd.z * DH + lane];
        acc += wd.w * vhead[(long long)jd.w * DH + lane];
    }
    out[qbase + lane] = acc;
}

extern "C" void kernel_launch(void* const* d_in, const int* in_sizes, int n_in,
                              void* d_out, int out_size, void* d_ws, size_t ws_size,
                              hipStream_t stream)
{
    const float* q   = (const float*)d_in[0];
    const float* k   = (const float*)d_in[1];
    const float* v   = (const float*)d_in[2];
    const float* etb = (const float*)d_in[3];
    const int* neigh_idx = (const int*)d_in[4];
    const int* edge_type = (const int*)d_in[5];
    float* out = (float*)d_out;

    const int total_queries = 16 * T_DIM;     // 32768
    const int blocks = total_queries / WPB;   // 8192
    const size_t need = (size_t)KV_ELEMS * 2 * sizeof(unsigned short); // 8 MB

    if (ws_size >= need) {
        unsigned int* ws = (unsigned int*)d_ws;
        hipLaunchKernelGGL(convert_kv_kernel, dim3(KV_ELEMS / 4 / 256), dim3(256),
                           0, stream, k, v, ws);
        hipLaunchKernelGGL(wayfinder_attn_f16, dim3(blocks), dim3(WPB * 64),
                           0, stream, q, ws, etb, neigh_idx, edge_type, out);
    } else {
        hipLaunchKernelGGL(wayfinder_attn_f32, dim3(blocks), dim3(WPB * 64),
                           0, stream, q, k, v, etb, neigh_idx, edge_type, out);
    }
}

// Round 8
// 117.738 us; speedup vs baseline: 1.8748x; 1.0393x over previous
//
#include <hip/hip_runtime.h>
#include <hip/hip_fp16.h>
#include <math.h>

// WayfinderAttention: B=1, H=16, T=2048, DH=64, D=64 neighbors. f32 in/out.
// R8: R7 skeleton (passed, absmax 0.0156) + two scheduling-only deltas:
//  (a) score phase: unconditional register prefetch of all 8 K uint4 chunks
//      (j_s zero-init -> entries >= nv read row 0, safe) => 8 loads in flight;
//      compute/capture unchanged (guarded, c8==i, blocked mapping).
//  (b) PV: quarter qw takes contiguous entries base+qw*4..+3 so j/w come as
//      int4/float4 broadcasts; V loads + f32 FMA math unchanged.
// Fallback to the proven R3 f32 kernel if ws_size < 8 MB.

#define T_DIM 2048
#define DH    64
#define NB    64
#define WPB   4
#define KV_ELEMS (16 * T_DIM * DH)   // 2,097,152 per tensor

typedef _Float16 h2_t __attribute__((ext_vector_type(2)));

// ---------------- prepass: f32 -> f16 (RTN), K then V ----------------
__global__ __launch_bounds__(256)
void convert_kv_kernel(const float* __restrict__ k, const float* __restrict__ v,
                       unsigned int* __restrict__ ws)
{
    const int tid = blockIdx.x * 256 + threadIdx.x;     // [0, KV_ELEMS/4)
    unsigned int* kh = ws;
    unsigned int* vh = ws + (KV_ELEMS / 2);
    const float4 kv = *(const float4*)(k + (long long)tid * 4);
    const float4 vv = *(const float4*)(v + (long long)tid * 4);
    h2_t k0 = { (_Float16)kv.x, (_Float16)kv.y };
    h2_t k1 = { (_Float16)kv.z, (_Float16)kv.w };
    h2_t v0 = { (_Float16)vv.x, (_Float16)vv.y };
    h2_t v1 = { (_Float16)vv.z, (_Float16)vv.w };
    uint2 pk, pv;
    pk.x = __builtin_bit_cast(unsigned int, k0);
    pk.y = __builtin_bit_cast(unsigned int, k1);
    pv.x = __builtin_bit_cast(unsigned int, v0);
    pv.y = __builtin_bit_cast(unsigned int, v1);
    *(uint2*)(kh + tid * 2) = pk;
    *(uint2*)(vh + tid * 2) = pv;
}

__device__ __forceinline__ float f16lo(unsigned int u) {
    return __low2float(__builtin_bit_cast(__half2, u));
}
__device__ __forceinline__ float f16hi(unsigned int u) {
    return __high2float(__builtin_bit_cast(__half2, u));
}

// ---------------- main kernel (f16 gathers, compacted; R7 structure) ----------------
__global__ __launch_bounds__(WPB * 64)
void wayfinder_attn_f16(const float* __restrict__ q,
                        const unsigned int* __restrict__ kvws,
                        const float* __restrict__ etb,
                        const int*   __restrict__ neigh_idx,
                        const int*   __restrict__ edge_type,
                        float*       __restrict__ out)
{
    __shared__ int   j_s[WPB][NB];
    __shared__ float b_s[WPB][NB];
    __shared__ float w_s[WPB][NB];

    const int lane = threadIdx.x & 63;
    const int wave = threadIdx.x >> 6;
    const int wq   = blockIdx.x * WPB + wave;       // flat h*T + t (B=1)
    const int t    = wq & (T_DIM - 1);
    const int qbase    = wq * DH;
    const int headbase = (wq - t) * DH;             // floats
    const unsigned int* __restrict__ kh = kvws + (headbase >> 1);
    const unsigned int* __restrict__ vh = kvws + (KV_ELEMS / 2) + (headbase >> 1);

    // init padding (entries >= nv read as row 0 / bias 0)
    j_s[wave][lane] = 0;
    b_s[wave][lane] = 0.f;

    // per-lane neighbor metadata (lane d owns raw neighbor slot d)
    const int raw = neigh_idx[wq * NB + lane];
    const int et  = edge_type[wq * NB + lane];
    const bool valid = (raw >= 0) && (raw <= t);
    const int  sj    = min(max(raw, 0), T_DIM - 1);
    const float bias = (et != 0) ? etb[et - 1] : 0.f;

    // compaction: valid entries -> positions [0, nv)
    const unsigned long long vb = __ballot(valid);
    const int nv  = __popcll(vb);
    const int pos = __popcll(vb & ((1ull << lane) - 1ull));
    if (valid) { j_s[wave][pos] = sj; b_s[wave][pos] = bias; }

    // ---- score phase: 8-lane groups, group g8 handles entries g8*8+i ----
    const int c8 = lane & 7;
    const int g8 = lane >> 3;
    const float4 qv0 = *(const float4*)(q + qbase + c8 * 8);
    const float4 qv1 = *(const float4*)(q + qbase + c8 * 8 + 4);

    int jarr[8];
    {
        const int4* jg = (const int4*)&j_s[wave][g8 * 8];
        *(int4*)&jarr[0] = jg[0];
        *(int4*)&jarr[4] = jg[1];
    }

    // (a) unconditional prefetch: 8 independent dwordx4 loads in flight.
    //     entries >= nv have jarr == 0 (row 0) -> safe address, L1-hot.
    uint4 kr[8];
    #pragma unroll
    for (int i = 0; i < 8; ++i) {
        kr[i] = *(const uint4*)(kh + jarr[i] * 32 + c8 * 4);  // dims 8c8..8c8+7
    }

    const int mycnt = nv - g8 * 8;   // group-uniform; may be <=0
    float mydot = 0.f;
    #pragma unroll
    for (int i = 0; i < 8; ++i) {
        if (i < mycnt) {
            const uint4 u = kr[i];
            float p = f16lo(u.x) * qv0.x + f16hi(u.x) * qv0.y
                    + f16lo(u.y) * qv0.z + f16hi(u.y) * qv0.w
                    + f16lo(u.z) * qv1.x + f16hi(u.z) * qv1.y
                    + f16lo(u.w) * qv1.z + f16hi(u.w) * qv1.w;
            p += __shfl_xor(p, 1, 64);
            p += __shfl_xor(p, 2, 64);
            p += __shfl_xor(p, 4, 64);
            if (c8 == i) mydot = p;   // lane g8*8+i == entry index e
        }
    }

    // ---- softmax over compacted entries (lane d = entry d) ----
    const bool dval = lane < nv;
    const float score = dval ? (mydot * 0.125f + b_s[wave][lane]) : -INFINITY;
    float m = score;
    #pragma unroll
    for (int o = 32; o > 0; o >>= 1) m = fmaxf(m, __shfl_xor(m, o, 64));
    const float e = dval ? __expf(score - m) : 0.f;
    float s = e;
    #pragma unroll
    for (int o = 32; o > 0; o >>= 1) s += __shfl_xor(s, o, 64);
    const float w = e / fmaxf(s, 1e-20f);
    w_s[wave][lane] = w;   // entries >= nv get w=0 (padding-safe)

    // ---- PV: quarter qw takes contiguous entries base+qw*4..+3 (vector LDS
    //      broadcasts); 16 lanes x 8B per V row; f32 accumulate ----
    const int qw   = lane >> 4;      // quarter 0..3
    const int lp16 = lane & 15;      // dims 4*lp16..4*lp16+3
    float a0 = 0.f, a1 = 0.f, a2 = 0.f, a3 = 0.f;
    for (int base = 0; base < nv; base += 16) {
        const int eb = base + qw * 4;
        const int4   jd = *(const int4*)&j_s[wave][eb];
        const float4 wd = *(const float4*)&w_s[wave][eb];
        const uint2 u0 = *(const uint2*)(vh + jd.x * 32 + lp16 * 2);
        const uint2 u1 = *(const uint2*)(vh + jd.y * 32 + lp16 * 2);
        const uint2 u2 = *(const uint2*)(vh + jd.z * 32 + lp16 * 2);
        const uint2 u3 = *(const uint2*)(vh + jd.w * 32 + lp16 * 2);
        a0 += wd.x * f16lo(u0.x);  a1 += wd.x * f16hi(u0.x);
        a2 += wd.x * f16lo(u0.y);  a3 += wd.x * f16hi(u0.y);
        a0 += wd.y * f16lo(u1.x);  a1 += wd.y * f16hi(u1.x);
        a2 += wd.y * f16lo(u1.y);  a3 += wd.y * f16hi(u1.y);
        a0 += wd.z * f16lo(u2.x);  a1 += wd.z * f16hi(u2.x);
        a2 += wd.z * f16lo(u2.y);  a3 += wd.z * f16hi(u2.y);
        a0 += wd.w * f16lo(u3.x);  a1 += wd.w * f16hi(u3.x);
        a2 += wd.w * f16lo(u3.y);  a3 += wd.w * f16hi(u3.y);
    }
    // reduce across quarters (butterfly), then lanes 0..15 store float4
    a0 += __shfl_xor(a0, 16, 64);  a1 += __shfl_xor(a1, 16, 64);
    a2 += __shfl_xor(a2, 16, 64);  a3 += __shfl_xor(a3, 16, 64);
    a0 += __shfl_xor(a0, 32, 64);  a1 += __shfl_xor(a1, 32, 64);
    a2 += __shfl_xor(a2, 32, 64);  a3 += __shfl_xor(a3, 32, 64);
    if (lane < 16) {
        float4 o; o.x = a0; o.y = a1; o.z = a2; o.w = a3;
        *(float4*)(out + qbase + lane * 4) = o;
    }
}

// ---------------- fallback (R3, f32, no workspace) ----------------
__global__ __launch_bounds__(WPB * 64)
void wayfinder_attn_f32(const float* __restrict__ q,
                        const float* __restrict__ k,
                        const float* __restrict__ v,
                        const float* __restrict__ etb,
                        const int*   __restrict__ neigh_idx,
                        const int*   __restrict__ edge_type,
                        float*       __restrict__ out)
{
    __shared__ int   j_s[WPB][NB];
    __shared__ float w_s[WPB][NB];

    const int lane = threadIdx.x & 63;
    const int wave = threadIdx.x >> 6;
    const int wq   = blockIdx.x * WPB + wave;
    const int t    = wq & (T_DIM - 1);
    const long long qbase    = (long long)wq * DH;
    const long long headbase = (long long)(wq - t) * DH;

    const long long nbase = (long long)wq * NB;
    const int raw = neigh_idx[nbase + lane];
    const int et  = edge_type[nbase + lane];
    const bool valid = (raw >= 0) && (raw <= t);
    const int  sj   = min(max(raw, 0), T_DIM - 1);
    j_s[wave][lane] = sj;

    const int c = lane & 15;
    const int g = lane >> 4;
    const float4 qv = *(const float4*)(q + qbase + c * 4);

    int jarr[16];
    {
        const int4* jg = (const int4*)&j_s[wave][g * 16];
        *(int4*)&jarr[0]  = jg[0];
        *(int4*)&jarr[4]  = jg[1];
        *(int4*)&jarr[8]  = jg[2];
        *(int4*)&jarr[12] = jg[3];
    }

    const float* __restrict__ khead = k + headbase;
    float mydot = 0.f;
    #pragma unroll
    for (int i = 0; i < 16; ++i) {
        const float4 kv = *(const float4*)(khead + (long long)jarr[i] * DH + c * 4);
        float p = kv.x * qv.x + kv.y * qv.y + kv.z * qv.z + kv.w * qv.w;
        p += __shfl_xor(p, 1, 64);
        p += __shfl_xor(p, 2, 64);
        p += __shfl_xor(p, 4, 64);
        p += __shfl_xor(p, 8, 64);
        if (c == i) mydot = p;
    }

    const float bias  = (et != 0) ? etb[et - 1] : 0.f;
    const float score = valid ? (mydot * 0.125f + bias) : -INFINITY;

    float m = score;
    #pragma unroll
    for (int o = 32; o > 0; o >>= 1) m = fmaxf(m, __shfl_xor(m, o, 64));
    const float e = valid ? __expf(score - m) : 0.f;
    float s = e;
    #pragma unroll
    for (int o = 32; o > 0; o >>= 1) s += __shfl_xor(s, o, 64);
    const float w = e / fmaxf(s, 1e-20f);
    w_s[wave][lane] = w;

    const float* __restrict__ vhead = v + headbase;
    float acc = 0.f;
    #pragma unroll
    for (int d4 = 0; d4 < 16; ++d4) {
        const float4 wd = *(const float4*)&w_s[wave][d4 * 4];
        const int4   jd = *(const int4*)&j_s[wave][d4 * 4];
        acc += wd.x * vhead[(long long)jd.x * DH + lane];
        acc += wd.y * vhead[(long long)jd.y * DH + lane];
        acc += wd.z * vhead[(long long)jd.z * DH + lane];
        acc += wd.w * vhead[(long long)jd.w * DH + lane];
    }
    out[qbase + lane] = acc;
}

extern "C" void kernel_launch(void* const* d_in, const int* in_sizes, int n_in,
                              void* d_out, int out_size, void* d_ws, size_t ws_size,
                              hipStream_t stream)
{
    const float* q   = (const float*)d_in[0];
    const float* k   = (const float*)d_in[1];
    const float* v   = (const float*)d_in[2];
    const float* etb = (const float*)d_in[3];
    const int* neigh_idx = (const int*)d_in[4];
    const int* edge_type = (const int*)d_in[5];
    float* out = (float*)d_out;

    const int total_queries = 16 * T_DIM;     // 32768
    const int blocks = total_queries / WPB;   // 8192
    const size_t need = (size_t)KV_ELEMS * 2 * sizeof(unsigned short); // 8 MB

    if (ws_size >= need) {
        unsigned int* ws = (unsigned int*)d_ws;
        hipLaunchKernelGGL(convert_kv_kernel, dim3(KV_ELEMS / 4 / 256), dim3(256),
                           0, stream, k, v, ws);
        hipLaunchKernelGGL(wayfinder_attn_f16, dim3(blocks), dim3(WPB * 64),
                           0, stream, q, ws, etb, neigh_idx, edge_type, out);
    } else {
        hipLaunchKernelGGL(wayfinder_attn_f32, dim3(blocks), dim3(WPB * 64),
                           0, stream, q, k, v, etb, neigh_idx, edge_type, out);
    }
}

// Round 9
// 112.873 us; speedup vs baseline: 1.9556x; 1.0431x over previous
//
#include <hip/hip_runtime.h>
#include <hip/hip_fp16.h>
#include <math.h>

// WayfinderAttention: B=1, H=16, T=2048, DH=64, D=64 neighbors. f32 in/out.
// R9: R8 (passed, absmax 0.0156) + SINGLE DELTA: interleaved score mapping.
//     Iteration i covers entries i*8..i*8+7 (group g8 handles e = i*8+g8),
//     so the guard i*8<nv is wave-uniform -> loop exits after ceil(nv/8)
//     iterations (avg ~4.6 of 8). Owner capture via LDS dot_s (lane c8==0 of
//     the computing group writes; lane e reads dot_s[e]). Per-entry dot
//     arithmetic/reduction order identical to R8 -> scores bitwise identical.
//     Everything else (f32 w, f32 PV, prefetch, vector PV) unchanged from R8.
// Fallback to the proven R3 f32 kernel if ws_size < 8 MB.

#define T_DIM 2048
#define DH    64
#define NB    64
#define WPB   4
#define KV_ELEMS (16 * T_DIM * DH)   // 2,097,152 per tensor

typedef _Float16 h2_t __attribute__((ext_vector_type(2)));

// ---------------- prepass: f32 -> f16 (RTN), K then V ----------------
__global__ __launch_bounds__(256)
void convert_kv_kernel(const float* __restrict__ k, const float* __restrict__ v,
                       unsigned int* __restrict__ ws)
{
    const int tid = blockIdx.x * 256 + threadIdx.x;     // [0, KV_ELEMS/4)
    unsigned int* kh = ws;
    unsigned int* vh = ws + (KV_ELEMS / 2);
    const float4 kv = *(const float4*)(k + (long long)tid * 4);
    const float4 vv = *(const float4*)(v + (long long)tid * 4);
    h2_t k0 = { (_Float16)kv.x, (_Float16)kv.y };
    h2_t k1 = { (_Float16)kv.z, (_Float16)kv.w };
    h2_t v0 = { (_Float16)vv.x, (_Float16)vv.y };
    h2_t v1 = { (_Float16)vv.z, (_Float16)vv.w };
    uint2 pk, pv;
    pk.x = __builtin_bit_cast(unsigned int, k0);
    pk.y = __builtin_bit_cast(unsigned int, k1);
    pv.x = __builtin_bit_cast(unsigned int, v0);
    pv.y = __builtin_bit_cast(unsigned int, v1);
    *(uint2*)(kh + tid * 2) = pk;
    *(uint2*)(vh + tid * 2) = pv;
}

__device__ __forceinline__ float f16lo(unsigned int u) {
    return __low2float(__builtin_bit_cast(__half2, u));
}
__device__ __forceinline__ float f16hi(unsigned int u) {
    return __high2float(__builtin_bit_cast(__half2, u));
}

// ---------------- main kernel (f16 gathers, compacted) ----------------
__global__ __launch_bounds__(WPB * 64)
void wayfinder_attn_f16(const float* __restrict__ q,
                        const unsigned int* __restrict__ kvws,
                        const float* __restrict__ etb,
                        const int*   __restrict__ neigh_idx,
                        const int*   __restrict__ edge_type,
                        float*       __restrict__ out)
{
    __shared__ int   j_s[WPB][NB];
    __shared__ float b_s[WPB][NB];
    __shared__ float w_s[WPB][NB];
    __shared__ float dot_s[WPB][NB];

    const int lane = threadIdx.x & 63;
    const int wave = threadIdx.x >> 6;
    const int wq   = blockIdx.x * WPB + wave;       // flat h*T + t (B=1)
    const int t    = wq & (T_DIM - 1);
    const int qbase    = wq * DH;
    const int headbase = (wq - t) * DH;             // floats
    const unsigned int* __restrict__ kh = kvws + (headbase >> 1);
    const unsigned int* __restrict__ vh = kvws + (KV_ELEMS / 2) + (headbase >> 1);

    // init padding (entries >= nv read as row 0 / bias 0)
    j_s[wave][lane] = 0;
    b_s[wave][lane] = 0.f;

    // per-lane neighbor metadata (lane d owns raw neighbor slot d)
    const int raw = neigh_idx[wq * NB + lane];
    const int et  = edge_type[wq * NB + lane];
    const bool valid = (raw >= 0) && (raw <= t);
    const int  sj    = min(max(raw, 0), T_DIM - 1);
    const float bias = (et != 0) ? etb[et - 1] : 0.f;

    // compaction: valid entries -> positions [0, nv)
    const unsigned long long vb = __ballot(valid);
    const int nv  = __popcll(vb);
    const int pos = __popcll(vb & ((1ull << lane) - 1ull));
    if (valid) { j_s[wave][pos] = sj; b_s[wave][pos] = bias; }

    // ---- score phase (interleaved): iteration i covers entries i*8..i*8+7;
    //      group g8 handles entry e = i*8+g8. Guard i*8<nv is wave-uniform. ----
    const int c8 = lane & 7;
    const int g8 = lane >> 3;
    const float4 qv0 = *(const float4*)(q + qbase + c8 * 8);
    const float4 qv1 = *(const float4*)(q + qbase + c8 * 8 + 4);

    // prefetch: up to ceil(nv/8) independent dwordx4 loads in flight.
    // j index read as scalar LDS broadcast (8 groups -> 8 distinct banks).
    uint4 kr[8];
    #pragma unroll
    for (int i = 0; i < 8; ++i) {
        if (i * 8 < nv) {
            const int je = j_s[wave][i * 8 + g8];   // entries >= nv -> row 0 (safe)
            kr[i] = *(const uint4*)(kh + je * 32 + c8 * 4);  // dims 8c8..8c8+7
        }
    }

    #pragma unroll
    for (int i = 0; i < 8; ++i) {
        if (i * 8 < nv) {
            const uint4 u = kr[i];
            float p = f16lo(u.x) * qv0.x + f16hi(u.x) * qv0.y
                    + f16lo(u.y) * qv0.z + f16hi(u.y) * qv0.w
                    + f16lo(u.z) * qv1.x + f16hi(u.z) * qv1.y
                    + f16lo(u.w) * qv1.z + f16hi(u.w) * qv1.w;
            p += __shfl_xor(p, 1, 64);
            p += __shfl_xor(p, 2, 64);
            p += __shfl_xor(p, 4, 64);
            if (c8 == 0) dot_s[wave][i * 8 + g8] = p;   // capture entry e
        }
    }
    const float mydot = dot_s[wave][lane];   // entry 'lane' (garbage if >= nv)

    // ---- softmax over compacted entries (lane d = entry d) ----
    const bool dval = lane < nv;
    const float score = dval ? (mydot * 0.125f + b_s[wave][lane]) : -INFINITY;
    float m = score;
    #pragma unroll
    for (int o = 32; o > 0; o >>= 1) m = fmaxf(m, __shfl_xor(m, o, 64));
    const float e = dval ? __expf(score - m) : 0.f;
    float s = e;
    #pragma unroll
    for (int o = 32; o > 0; o >>= 1) s += __shfl_xor(s, o, 64);
    const float w = e / fmaxf(s, 1e-20f);
    w_s[wave][lane] = w;   // entries >= nv get w=0 (padding-safe)

    // ---- PV: quarter qw takes contiguous entries base+qw*4..+3 (vector LDS
    //      broadcasts); 16 lanes x 8B per V row; f32 accumulate ----
    const int qw   = lane >> 4;      // quarter 0..3
    const int lp16 = lane & 15;      // dims 4*lp16..4*lp16+3
    float a0 = 0.f, a1 = 0.f, a2 = 0.f, a3 = 0.f;
    for (int base = 0; base < nv; base += 16) {
        const int eb = base + qw * 4;
        const int4   jd = *(const int4*)&j_s[wave][eb];
        const float4 wd = *(const float4*)&w_s[wave][eb];
        const uint2 u0 = *(const uint2*)(vh + jd.x * 32 + lp16 * 2);
        const uint2 u1 = *(const uint2*)(vh + jd.y * 32 + lp16 * 2);
        const uint2 u2 = *(const uint2*)(vh + jd.z * 32 + lp16 * 2);
        const uint2 u3 = *(const uint2*)(vh + jd.w * 32 + lp16 * 2);
        a0 += wd.x * f16lo(u0.x);  a1 += wd.x * f16hi(u0.x);
        a2 += wd.x * f16lo(u0.y);  a3 += wd.x * f16hi(u0.y);
        a0 += wd.y * f16lo(u1.x);  a1 += wd.y * f16hi(u1.x);
        a2 += wd.y * f16lo(u1.y);  a3 += wd.y * f16hi(u1.y);
        a0 += wd.z * f16lo(u2.x);  a1 += wd.z * f16hi(u2.x);
        a2 += wd.z * f16lo(u2.y);  a3 += wd.z * f16hi(u2.y);
        a0 += wd.w * f16lo(u3.x);  a1 += wd.w * f16hi(u3.x);
        a2 += wd.w * f16lo(u3.y);  a3 += wd.w * f16hi(u3.y);
    }
    // reduce across quarters (butterfly), then lanes 0..15 store float4
    a0 += __shfl_xor(a0, 16, 64);  a1 += __shfl_xor(a1, 16, 64);
    a2 += __shfl_xor(a2, 16, 64);  a3 += __shfl_xor(a3, 16, 64);
    a0 += __shfl_xor(a0, 32, 64);  a1 += __shfl_xor(a1, 32, 64);
    a2 += __shfl_xor(a2, 32, 64);  a3 += __shfl_xor(a3, 32, 64);
    if (lane < 16) {
        float4 o; o.x = a0; o.y = a1; o.z = a2; o.w = a3;
        *(float4*)(out + qbase + lane * 4) = o;
    }
}

// ---------------- fallback (R3, f32, no workspace) ----------------
__global__ __launch_bounds__(WPB * 64)
void wayfinder_attn_f32(const float* __restrict__ q,
                        const float* __restrict__ k,
                        const float* __restrict__ v,
                        const float* __restrict__ etb,
                        const int*   __restrict__ neigh_idx,
                        const int*   __restrict__ edge_type,
                        float*       __restrict__ out)
{
    __shared__ int   j_s[WPB][NB];
    __shared__ float w_s[WPB][NB];

    const int lane = threadIdx.x & 63;
    const int wave = threadIdx.x >> 6;
    const int wq   = blockIdx.x * WPB + wave;
    const int t    = wq & (T_DIM - 1);
    const long long qbase    = (long long)wq * DH;
    const long long headbase = (long long)(wq - t) * DH;

    const long long nbase = (long long)wq * NB;
    const int raw = neigh_idx[nbase + lane];
    const int et  = edge_type[nbase + lane];
    const bool valid = (raw >= 0) && (raw <= t);
    const int  sj   = min(max(raw, 0), T_DIM - 1);
    j_s[wave][lane] = sj;

    const int c = lane & 15;
    const int g = lane >> 4;
    const float4 qv = *(const float4*)(q + qbase + c * 4);

    int jarr[16];
    {
        const int4* jg = (const int4*)&j_s[wave][g * 16];
        *(int4*)&jarr[0]  = jg[0];
        *(int4*)&jarr[4]  = jg[1];
        *(int4*)&jarr[8]  = jg[2];
        *(int4*)&jarr[12] = jg[3];
    }

    const float* __restrict__ khead = k + headbase;
    float mydot = 0.f;
    #pragma unroll
    for (int i = 0; i < 16; ++i) {
        const float4 kv = *(const float4*)(khead + (long long)jarr[i] * DH + c * 4);
        float p = kv.x * qv.x + kv.y * qv.y + kv.z * qv.z + kv.w * qv.w;
        p += __shfl_xor(p, 1, 64);
        p += __shfl_xor(p, 2, 64);
        p += __shfl_xor(p, 4, 64);
        p += __shfl_xor(p, 8, 64);
        if (c == i) mydot = p;
    }

    const float bias  = (et != 0) ? etb[et - 1] : 0.f;
    const float score = valid ? (mydot * 0.125f + bias) : -INFINITY;

    float m = score;
    #pragma unroll
    for (int o = 32; o > 0; o >>= 1) m = fmaxf(m, __shfl_xor(m, o, 64));
    const float e = valid ? __expf(score - m) : 0.f;
    float s = e;
    #pragma unroll
    for (int o = 32; o > 0; o >>= 1) s += __shfl_xor(s, o, 64);
    const float w = e / fmaxf(s, 1e-20f);
    w_s[wave][lane] = w;

    const float* __restrict__ vhead = v + headbase;
    float acc = 0.f;
    #pragma unroll
    for (int d4 = 0; d4 < 16; ++d4) {
        const float4 wd = *(const float4*)&w_s[wave][d4 * 4];
        const int4   jd = *(const int4*)&j_s[wave][d4 * 4];
        acc += wd.x * vhead[(long long)jd.x * DH + lane];
        acc += wd.y * vhead[(long long)jd.y * DH + lane];
        acc += wd.z * vhead[(long long)jd.z * DH + lane];
        acc += wd.w * vhead[(long long)jd.w * DH + lane];
    }
    out[qbase + lane] = acc;
}

extern "C" void kernel_launch(void* const* d_in, const int* in_sizes, int n_in,
                              void* d_out, int out_size, void* d_ws, size_t ws_size,
                              hipStream_t stream)
{
    const float* q   = (const float*)d_in[0];
    const float* k   = (const float*)d_in[1];
    const float* v   = (const float*)d_in[2];
    const float* etb = (const float*)d_in[3];
    const int* neigh_idx = (const int*)d_in[4];
    const int* edge_type = (const int*)d_in[5];
    float* out = (float*)d_out;

    const int total_queries = 16 * T_DIM;     // 32768
    const int blocks = total_queries / WPB;   // 8192
    const size_t need = (size_t)KV_ELEMS * 2 * sizeof(unsigned short); // 8 MB

    if (ws_size >= need) {
        unsigned int* ws = (unsigned int*)d_ws;
        hipLaunchKernelGGL(convert_kv_kernel, dim3(KV_ELEMS / 4 / 256), dim3(256),
                           0, stream, k, v, ws);
        hipLaunchKernelGGL(wayfinder_attn_f16, dim3(blocks), dim3(WPB * 64),
                           0, stream, q, ws, etb, neigh_idx, edge_type, out);
    } else {
        hipLaunchKernelGGL(wayfinder_attn_f32, dim3(blocks), dim3(WPB * 64),
                           0, stream, q, k, v, etb, neigh_idx, edge_type, out);
    }
}

// Round 10
// 111.855 us; speedup vs baseline: 1.9734x; 1.0091x over previous
//
#include <hip/hip_runtime.h>
#include <hip/hip_fp16.h>
#include <math.h>

// WayfinderAttention: B=1, H=16, T=2048, DH=64, D=64 neighbors. f32 in/out.
// R10: R9 (passed, absmax 0.0156, total 112.9us) + SINGLE DELTA:
//      score inner product via v_dot2_f32_f16 (__builtin_amdgcn_fdot2) with
//      q pre-rounded to packed f16 -> 4 dot ops replace 8 cvt + 8 fma per
//      8-dim chunk. Fallback path reproduces R9 numerics exactly.
//      PV stays f32-weight / f32-accumulate (half-accum PV was the R5/R6 bug).
// Fallback to the proven R3 f32 kernel if ws_size < 8 MB.

#define T_DIM 2048
#define DH    64
#define NB    64
#define WPB   4
#define KV_ELEMS (16 * T_DIM * DH)   // 2,097,152 per tensor

typedef _Float16 h2_t __attribute__((ext_vector_type(2)));

// ---------------- prepass: f32 -> f16 (RTN), K then V ----------------
__global__ __launch_bounds__(256)
void convert_kv_kernel(const float* __restrict__ k, const float* __restrict__ v,
                       unsigned int* __restrict__ ws)
{
    const int tid = blockIdx.x * 256 + threadIdx.x;     // [0, KV_ELEMS/4)
    unsigned int* kh = ws;
    unsigned int* vh = ws + (KV_ELEMS / 2);
    const float4 kv = *(const float4*)(k + (long long)tid * 4);
    const float4 vv = *(const float4*)(v + (long long)tid * 4);
    h2_t k0 = { (_Float16)kv.x, (_Float16)kv.y };
    h2_t k1 = { (_Float16)kv.z, (_Float16)kv.w };
    h2_t v0 = { (_Float16)vv.x, (_Float16)vv.y };
    h2_t v1 = { (_Float16)vv.z, (_Float16)vv.w };
    uint2 pk, pv;
    pk.x = __builtin_bit_cast(unsigned int, k0);
    pk.y = __builtin_bit_cast(unsigned int, k1);
    pv.x = __builtin_bit_cast(unsigned int, v0);
    pv.y = __builtin_bit_cast(unsigned int, v1);
    *(uint2*)(kh + tid * 2) = pk;
    *(uint2*)(vh + tid * 2) = pv;
}

__device__ __forceinline__ float f16lo(unsigned int u) {
    return __low2float(__builtin_bit_cast(__half2, u));
}
__device__ __forceinline__ float f16hi(unsigned int u) {
    return __high2float(__builtin_bit_cast(__half2, u));
}

__device__ __forceinline__ float dot2f(unsigned int ku, h2_t qh, float c) {
#if __has_builtin(__builtin_amdgcn_fdot2)
    return __builtin_amdgcn_fdot2(__builtin_bit_cast(h2_t, ku), qh, c, false);
#else
    return c + f16lo(ku) * (float)qh.x + f16hi(ku) * (float)qh.y;
#endif
}

// ---------------- main kernel (f16 gathers, compacted) ----------------
__global__ __launch_bounds__(WPB * 64)
void wayfinder_attn_f16(const float* __restrict__ q,
                        const unsigned int* __restrict__ kvws,
                        const float* __restrict__ etb,
                        const int*   __restrict__ neigh_idx,
                        const int*   __restrict__ edge_type,
                        float*       __restrict__ out)
{
    __shared__ int   j_s[WPB][NB];
    __shared__ float b_s[WPB][NB];
    __shared__ float w_s[WPB][NB];
    __shared__ float dot_s[WPB][NB];

    const int lane = threadIdx.x & 63;
    const int wave = threadIdx.x >> 6;
    const int wq   = blockIdx.x * WPB + wave;       // flat h*T + t (B=1)
    const int t    = wq & (T_DIM - 1);
    const int qbase    = wq * DH;
    const int headbase = (wq - t) * DH;             // floats
    const unsigned int* __restrict__ kh = kvws + (headbase >> 1);
    const unsigned int* __restrict__ vh = kvws + (KV_ELEMS / 2) + (headbase >> 1);

    // init padding (entries >= nv read as row 0 / bias 0)
    j_s[wave][lane] = 0;
    b_s[wave][lane] = 0.f;

    // per-lane neighbor metadata (lane d owns raw neighbor slot d)
    const int raw = neigh_idx[wq * NB + lane];
    const int et  = edge_type[wq * NB + lane];
    const bool valid = (raw >= 0) && (raw <= t);
    const int  sj    = min(max(raw, 0), T_DIM - 1);
    const float bias = (et != 0) ? etb[et - 1] : 0.f;

    // compaction: valid entries -> positions [0, nv)
    const unsigned long long vb = __ballot(valid);
    const int nv  = __popcll(vb);
    const int pos = __popcll(vb & ((1ull << lane) - 1ull));
    if (valid) { j_s[wave][pos] = sj; b_s[wave][pos] = bias; }

    // ---- score phase (interleaved): iteration i covers entries i*8..i*8+7;
    //      group g8 handles entry e = i*8+g8. Guard i*8<nv is wave-uniform. ----
    const int c8 = lane & 7;
    const int g8 = lane >> 3;
    const float4 qv0 = *(const float4*)(q + qbase + c8 * 8);
    const float4 qv1 = *(const float4*)(q + qbase + c8 * 8 + 4);
    // q pre-rounded to packed f16 for v_dot2_f32_f16 (adds ~1e-3 to scores)
    const h2_t qh0 = { (_Float16)qv0.x, (_Float16)qv0.y };
    const h2_t qh1 = { (_Float16)qv0.z, (_Float16)qv0.w };
    const h2_t qh2 = { (_Float16)qv1.x, (_Float16)qv1.y };
    const h2_t qh3 = { (_Float16)qv1.z, (_Float16)qv1.w };

    // prefetch: up to ceil(nv/8) independent dwordx4 loads in flight.
    uint4 kr[8];
    #pragma unroll
    for (int i = 0; i < 8; ++i) {
        if (i * 8 < nv) {
            const int je = j_s[wave][i * 8 + g8];   // entries >= nv -> row 0 (safe)
            kr[i] = *(const uint4*)(kh + je * 32 + c8 * 4);  // dims 8c8..8c8+7
        }
    }

    #pragma unroll
    for (int i = 0; i < 8; ++i) {
        if (i * 8 < nv) {
            const uint4 u = kr[i];
            float p = dot2f(u.x, qh0, 0.f);
            p = dot2f(u.y, qh1, p);
            p = dot2f(u.z, qh2, p);
            p = dot2f(u.w, qh3, p);
            p += __shfl_xor(p, 1, 64);
            p += __shfl_xor(p, 2, 64);
            p += __shfl_xor(p, 4, 64);
            if (c8 == 0) dot_s[wave][i * 8 + g8] = p;   // capture entry e
        }
    }
    const float mydot = dot_s[wave][lane];   // entry 'lane' (garbage if >= nv)

    // ---- softmax over compacted entries (lane d = entry d) ----
    const bool dval = lane < nv;
    const float score = dval ? (mydot * 0.125f + b_s[wave][lane]) : -INFINITY;
    float m = score;
    #pragma unroll
    for (int o = 32; o > 0; o >>= 1) m = fmaxf(m, __shfl_xor(m, o, 64));
    const float e = dval ? __expf(score - m) : 0.f;
    float s = e;
    #pragma unroll
    for (int o = 32; o > 0; o >>= 1) s += __shfl_xor(s, o, 64);
    const float w = e / fmaxf(s, 1e-20f);
    w_s[wave][lane] = w;   // entries >= nv get w=0 (padding-safe)

    // ---- PV: quarter qw takes contiguous entries base+qw*4..+3 (vector LDS
    //      broadcasts); 16 lanes x 8B per V row; f32 accumulate ----
    const int qw   = lane >> 4;      // quarter 0..3
    const int lp16 = lane & 15;      // dims 4*lp16..4*lp16+3
    float a0 = 0.f, a1 = 0.f, a2 = 0.f, a3 = 0.f;
    for (int base = 0; base < nv; base += 16) {
        const int eb = base + qw * 4;
        const int4   jd = *(const int4*)&j_s[wave][eb];
        const float4 wd = *(const float4*)&w_s[wave][eb];
        const uint2 u0 = *(const uint2*)(vh + jd.x * 32 + lp16 * 2);
        const uint2 u1 = *(const uint2*)(vh + jd.y * 32 + lp16 * 2);
        const uint2 u2 = *(const uint2*)(vh + jd.z * 32 + lp16 * 2);
        const uint2 u3 = *(const uint2*)(vh + jd.w * 32 + lp16 * 2);
        a0 += wd.x * f16lo(u0.x);  a1 += wd.x * f16hi(u0.x);
        a2 += wd.x * f16lo(u0.y);  a3 += wd.x * f16hi(u0.y);
        a0 += wd.y * f16lo(u1.x);  a1 += wd.y * f16hi(u1.x);
        a2 += wd.y * f16lo(u1.y);  a3 += wd.y * f16hi(u1.y);
        a0 += wd.z * f16lo(u2.x);  a1 += wd.z * f16hi(u2.x);
        a2 += wd.z * f16lo(u2.y);  a3 += wd.z * f16hi(u2.y);
        a0 += wd.w * f16lo(u3.x);  a1 += wd.w * f16hi(u3.x);
        a2 += wd.w * f16lo(u3.y);  a3 += wd.w * f16hi(u3.y);
    }
    // reduce across quarters (butterfly), then lanes 0..15 store float4
    a0 += __shfl_xor(a0, 16, 64);  a1 += __shfl_xor(a1, 16, 64);
    a2 += __shfl_xor(a2, 16, 64);  a3 += __shfl_xor(a3, 16, 64);
    a0 += __shfl_xor(a0, 32, 64);  a1 += __shfl_xor(a1, 32, 64);
    a2 += __shfl_xor(a2, 32, 64);  a3 += __shfl_xor(a3, 32, 64);
    if (lane < 16) {
        float4 o; o.x = a0; o.y = a1; o.z = a2; o.w = a3;
        *(float4*)(out + qbase + lane * 4) = o;
    }
}

// ---------------- fallback (R3, f32, no workspace) ----------------
__global__ __launch_bounds__(WPB * 64)
void wayfinder_attn_f32(const float* __restrict__ q,
                        const float* __restrict__ k,
                        const float* __restrict__ v,
                        const float* __restrict__ etb,
                        const int*   __restrict__ neigh_idx,
                        const int*   __restrict__ edge_type,
                        float*       __restrict__ out)
{
    __shared__ int   j_s[WPB][NB];
    __shared__ float w_s[WPB][NB];

    const int lane = threadIdx.x & 63;
    const int wave = threadIdx.x >> 6;
    const int wq   = blockIdx.x * WPB + wave;
    const int t    = wq & (T_DIM - 1);
    const long long qbase    = (long long)wq * DH;
    const long long headbase = (long long)(wq - t) * DH;

    const long long nbase = (long long)wq * NB;
    const int raw = neigh_idx[nbase + lane];
    const int et  = edge_type[nbase + lane];
    const bool valid = (raw >= 0) && (raw <= t);
    const int  sj   = min(max(raw, 0), T_DIM - 1);
    j_s[wave][lane] = sj;

    const int c = lane & 15;
    const int g = lane >> 4;
    const float4 qv = *(const float4*)(q + qbase + c * 4);

    int jarr[16];
    {
        const int4* jg = (const int4*)&j_s[wave][g * 16];
        *(int4*)&jarr[0]  = jg[0];
        *(int4*)&jarr[4]  = jg[1];
        *(int4*)&jarr[8]  = jg[2];
        *(int4*)&jarr[12] = jg[3];
    }

    const float* __restrict__ khead = k + headbase;
    float mydot = 0.f;
    #pragma unroll
    for (int i = 0; i < 16; ++i) {
        const float4 kv = *(const float4*)(khead + (long long)jarr[i] * DH + c * 4);
        float p = kv.x * qv.x + kv.y * qv.y + kv.z * qv.z + kv.w * qv.w;
        p += __shfl_xor(p, 1, 64);
        p += __shfl_xor(p, 2, 64);
        p += __shfl_xor(p, 4, 64);
        p += __shfl_xor(p, 8, 64);
        if (c == i) mydot = p;
    }

    const float bias  = (et != 0) ? etb[et - 1] : 0.f;
    const float score = valid ? (mydot * 0.125f + bias) : -INFINITY;

    float m = score;
    #pragma unroll
    for (int o = 32; o > 0; o >>= 1) m = fmaxf(m, __shfl_xor(m, o, 64));
    const float e = valid ? __expf(score - m) : 0.f;
    float s = e;
    #pragma unroll
    for (int o = 32; o > 0; o >>= 1) s += __shfl_xor(s, o, 64);
    const float w = e / fmaxf(s, 1e-20f);
    w_s[wave][lane] = w;

    const float* __restrict__ vhead = v + headbase;
    float acc = 0.f;
    #pragma unroll
    for (int d4 = 0; d4 < 16; ++d4) {
        const float4 wd = *(const float4*)&w_s[wave][d4 * 4];
        const int4   jd = *(const int4*)&j_s[wave][d4 * 4];
        acc += wd.x * vhead[(long long)jd.x * DH + lane];
        acc += wd.y * vhead[(long long)jd.y * DH + lane];
        acc += wd.z * vhead[(long long)jd.z * DH + lane];
        acc += wd.w * vhead[(long long)jd.w * DH + lane];
    }
    out[qbase + lane] = acc;
}

extern "C" void kernel_launch(void* const* d_in, const int* in_sizes, int n_in,
                              void* d_out, int out_size, void* d_ws, size_t ws_size,
                              hipStream_t stream)
{
    const float* q   = (const float*)d_in[0];
    const float* k   = (const float*)d_in[1];
    const float* v   = (const float*)d_in[2];
    const float* etb = (const float*)d_in[3];
    const int* neigh_idx = (const int*)d_in[4];
    const int* edge_type = (const int*)d_in[5];
    float* out = (float*)d_out;

    const int total_queries = 16 * T_DIM;     // 32768
    const int blocks = total_queries / WPB;   // 8192
    const size_t need = (size_t)KV_ELEMS * 2 * sizeof(unsigned short); // 8 MB

    if (ws_size >= need) {
        unsigned int* ws = (unsigned int*)d_ws;
        hipLaunchKernelGGL(convert_kv_kernel, dim3(KV_ELEMS / 4 / 256), dim3(256),
                           0, stream, k, v, ws);
        hipLaunchKernelGGL(wayfinder_attn_f16, dim3(blocks), dim3(WPB * 64),
                           0, stream, q, ws, etb, neigh_idx, edge_type, out);
    } else {
        hipLaunchKernelGGL(wayfinder_attn_f32, dim3(blocks), dim3(WPB * 64),
                           0, stream, q, k, v, etb, neigh_idx, edge_type, out);
    }
}